// Round 15
// baseline (132.467 us; speedup 1.0000x reference)
//
#include <hip/hip_runtime.h>
#include <cfloat>

typedef unsigned long long u64;

#define CDESC 32
#define N0 4096
#define N1 512

// sign-transformed float bits: monotone u32 over the float total order
__device__ __forceinline__ unsigned fbits_mono(float d) {
    unsigned b = __float_as_uint(d);
    return (d >= 0.f) ? (b | 0x80000000u) : ~b;
}

__device__ __forceinline__ void wave_reduce_atomic(float v, float* acc) {
#pragma unroll
    for (int off = 32; off > 0; off >>= 1) v += __shfl_down(v, off, 64);
    if ((threadIdx.x & 63) == 0) atomicAdd(acc, v);
}

// ======================= K1: fused x-filter (both stages) + transpose =======================
// blocks 0..767 (x2 sides): one (channel, z) input plane staged to LDS once;
// compute BOTH S=16 (R=4) and S=8 (R=8) x-filter outputs (input read once).
// blocks 768..1055: descriptor transpose [b][32][N] -> [b][N][32].
// Inits acc / group tickets / argmin slots (0xAA poison is NOT max key).
__global__ __launch_bounds__(256) void pass1_fused(
        const float* __restrict__ csrc, const float* __restrict__ ctgt,
        const float* __restrict__ sd0, const float* __restrict__ td0,
        const float* __restrict__ sd1, const float* __restrict__ td1,
        float* __restrict__ t16a, float* __restrict__ t16b,
        float* __restrict__ t8a,  float* __restrict__ t8b,
        float* __restrict__ sd0T, float* __restrict__ td0T,
        float* __restrict__ sd1T, float* __restrict__ td1T,
        float* __restrict__ acc, unsigned* __restrict__ tick,
        u64* __restrict__ slot) {
    __shared__ __align__(16) float sRow[4096];     // one 64x64 plane (16 KB)
    const int tid = threadIdx.x;
    const int bx  = blockIdx.x, by = blockIdx.y;
    if (by == 0) {                                 // init side
        int gid = bx * 256 + tid;
        if (gid < 4) acc[gid] = 0.f;
        if (gid < 128) tick[gid] = 0u;
        if (gid < 16384) slot[gid] = ~0ull;
    }

    if (bx < 768) {
        int bc = bx >> 6, z = bx & 63;             // channel-plane, z-slice
        const float* in = by ? ctgt : csrc;
        float* o16 = by ? t16b : t16a;
        float* o8  = by ? t8b  : t8a;
        const float4* src = (const float4*)(in + (size_t)(bc * 64 + z) * 4096);
        float4* dst = (float4*)sRow;
#pragma unroll
        for (int k = 0; k < 4; ++k)                // coalesced 16 KB stage
            dst[tid + k * 256] = src[tid + k * 256];
        __syncthreads();
#pragma unroll
        for (int k = 0; k < 6; ++k) {              // 1536 outputs, 6/thread
            int o = tid + k * 256;
            if (o < 1024) {                        // S=16, R=4 (k=0..3: no divergence)
                int y = o >> 4, xo = o & 15;
                int j0 = 4 * xo - 2;
                float sum = 0.f, wsum = 0.f;
#pragma unroll
                for (int t = 0; t < 8; ++t) {
                    int j = j0 + t;
                    float w = 1.f - fabsf((float)t - 3.5f) / 4.f;
                    if (j >= 0 && j < 64) { sum = fmaf(w, sRow[y * 64 + j], sum); wsum += w; }
                }
                o16[bc * 65536 + z * 1024 + y * 16 + xo] = sum / wsum;
            } else {                               // S=8, R=8 (k=4,5)
                int o2 = o - 1024;
                int y = o2 >> 3, xo = o2 & 7;
                int j0 = 8 * xo - 4;
                float sum = 0.f, wsum = 0.f;
#pragma unroll
                for (int t = 0; t < 16; ++t) {
                    int j = j0 + t;
                    float w = 1.f - fabsf((float)t - 7.5f) / 8.f;
                    if (j >= 0 && j < 64) { sum = fmaf(w, sRow[y * 64 + j], sum); wsum += w; }
                }
                o8[bc * 32768 + z * 512 + y * 8 + xo] = sum / wsum;
            }
        }
    } else {
        // ---- transpose [b][32][N] -> [b][N][32], 64-point tiles (verified R7) ----
        __shared__ float tile[64 * 33];
        int tl = bx - 768;                         // 0..287
        const float* din; float* dout; int N, b, n0;
        if (tl < 256) { din = by ? td0 : sd0; dout = by ? td0T : sd0T;
                        N = N0; b = tl >> 6; n0 = (tl & 63) * 64; }
        else { tl -= 256; din = by ? td1 : sd1; dout = by ? td1T : sd1T;
               N = N1; b = tl >> 3; n0 = (tl & 7) * 64; }
#pragma unroll
        for (int i = 0; i < 8; ++i) {              // load: coalesced 64-float rows
            int idx = tid + i * 256;
            int c = idx >> 6, j = idx & 63;
            tile[j * 33 + c] = din[((size_t)b * CDESC + c) * N + n0 + j];
        }
        __syncthreads();
#pragma unroll
        for (int i = 0; i < 8; ++i) {              // store: contiguous 32-float points
            int idx = tid + i * 256;
            int p = idx >> 5, c = idx & 31;
            dout[((size_t)b * N + n0 + p) * CDESC + c] = tile[p * 33 + c];
        }
    }
}

// K2: both stages' y/z-filter, 8 sub-threads per point (verified R6/R7).
__global__ __launch_bounds__(256) void pass2_both(
        const float* __restrict__ t16a, const float* __restrict__ t16b,
        const float* __restrict__ t8a,  const float* __restrict__ t8b,
        float4* __restrict__ ps0, float4* __restrict__ pt0,
        float4* __restrict__ ps1, float4* __restrict__ pt1) {
    int gid = blockIdx.x * 256 + threadIdx.x;
    if (blockIdx.x < 1024) {
        int sub = gid & 7, p = gid >> 3;
        int side = p >> 14, r = p & 16383;
        int b = r >> 12, n = r & 4095;
        int x = n & 15, y = (n >> 4) & 15, z = n >> 8;
        const float* t = side ? t16b : t16a;
        float wy[8]; int jy[8];
        float wys = 0.f, wzs = 0.f;
#pragma unroll
        for (int tt = 0; tt < 8; ++tt) {
            float w = 1.f - fabsf((float)tt - 3.5f) * 0.25f;
            int j = 4 * y - 2 + tt;
            bool v = (unsigned)j < 64u;
            wy[tt] = v ? w : 0.f; jy[tt] = v ? j : 0; wys += wy[tt];
            int jz = 4 * z - 2 + tt;
            if ((unsigned)jz < 64u) wzs += w;
        }
        float a0 = 0.f, a1 = 0.f, a2 = 0.f;
        {
            float wz = 1.f - fabsf((float)sub - 3.5f) * 0.25f;
            int jz = 4 * z - 2 + sub;
            if ((unsigned)jz < 64u) {
                const float* bz = t + (size_t)b * 196608 + jz * 1024 + x;
#pragma unroll
                for (int ty = 0; ty < 8; ++ty) {
                    float w = wz * wy[ty];
                    const float* pr = bz + jy[ty] * 16;
                    a0 = fmaf(w, pr[0],      a0);
                    a1 = fmaf(w, pr[65536],  a1);
                    a2 = fmaf(w, pr[131072], a2);
                }
            }
        }
#pragma unroll
        for (int m = 1; m < 8; m <<= 1) {
            a0 += __shfl_xor(a0, m, 64);
            a1 += __shfl_xor(a1, m, 64);
            a2 += __shfl_xor(a2, m, 64);
        }
        if (sub == 0) {
            float inv = 1.f / (wys * wzs);
            a0 *= inv; a1 *= inv; a2 *= inv;
            float4* pts = side ? pt0 : ps0;
            pts[b * N0 + n] = make_float4(a0, a1, a2, a0 * a0 + a1 * a1 + a2 * a2);
        }
    } else {
        int g = gid - 262144;
        int sub = g & 7, p = g >> 3;
        int side = p >> 11, r = p & 2047;
        int b = r >> 9, n = r & 511;
        int x = n & 7, y = (n >> 3) & 7, z = n >> 6;
        const float* t = side ? t8b : t8a;
        constexpr int CS = 64 * 64 * 8;
        float wy[16]; int jy[16];
        float wys = 0.f, wzs = 0.f;
#pragma unroll
        for (int tt = 0; tt < 16; ++tt) {
            float w = 1.f - fabsf((float)tt - 7.5f) * 0.125f;
            int j = 8 * y - 4 + tt;
            bool v = (unsigned)j < 64u;
            wy[tt] = v ? w : 0.f; jy[tt] = v ? j : 0; wys += wy[tt];
            int jz = 8 * z - 4 + tt;
            if ((unsigned)jz < 64u) wzs += w;
        }
        float a0 = 0.f, a1 = 0.f, a2 = 0.f;
#pragma unroll
        for (int k = 0; k < 2; ++k) {
            int tt = 2 * sub + k;
            float wz = 1.f - fabsf((float)tt - 7.5f) * 0.125f;
            int jz = 8 * z - 4 + tt;
            if ((unsigned)jz < 64u) {
                const float* bz = t + b * 3 * CS + jz * (64 * 8) + x;
#pragma unroll 1
                for (int ty = 0; ty < 16; ++ty) {
                    float w = wz * wy[ty];
                    const float* pr = bz + jy[ty] * 8;
                    a0 = fmaf(w, pr[0],      a0);
                    a1 = fmaf(w, pr[CS],     a1);
                    a2 = fmaf(w, pr[2 * CS], a2);
                }
            }
        }
#pragma unroll
        for (int m = 1; m < 8; m <<= 1) {
            a0 += __shfl_xor(a0, m, 64);
            a1 += __shfl_xor(a1, m, 64);
            a2 += __shfl_xor(a2, m, 64);
        }
        if (sub == 0) {
            float inv = 1.f / (wys * wzs);
            a0 *= inv; a1 *= inv; a2 *= inv;
            float4* pts = side ? pt1 : ps1;
            pts[b * N1 + n] = make_float4(a0, a1, a2, a0 * a0 + a1 * a1 + a2 * a2);
        }
    }
}

// cosine of two point-major 32-float descriptors (coalesced float4 reads)
__device__ __forceinline__ float cos_pm(const float* __restrict__ sT,
                                        const float* __restrict__ tT,
                                        size_t si, size_t ti) {
    const float4* s = (const float4*)(sT + si * CDESC);
    const float4* t = (const float4*)(tT + ti * CDESC);
    float num = 0.f, s2 = 0.f, t2 = 0.f;
#pragma unroll
    for (int c = 0; c < 8; ++c) {
        float4 a = s[c], g = t[c];
        num = fmaf(a.x, g.x, fmaf(a.y, g.y, fmaf(a.z, g.z, fmaf(a.w, g.w, num))));
        s2  = fmaf(a.x, a.x, fmaf(a.y, a.y, fmaf(a.z, a.z, fmaf(a.w, a.w, s2))));
        t2  = fmaf(g.x, g.x, fmaf(g.y, g.y, fmaf(g.z, g.z, fmaf(g.w, g.w, t2))));
    }
    return num / (fmaxf(sqrtf(s2), 1e-8f) * fmaxf(sqrtf(t2), 1e-8f));
}

// ======================= K3: argmin + cosine, 2 pts/lane, quarter-targets, 2 blocks/CU =======================
// blocks 0..511: stage-0, block = (b, 128-pt group g, target-quarter tq).
//   Stage 1024 pre-scaled targets (16 KB LDS -> 2 blocks/CU co-resident, so
//   staging/combine/tail overlap the other block's scan). 4 waves x 256-target
//   windows; 2 src pts/lane -> each broadcast ds_read_b128 serves 128 pts:
//   LDS reads/CU = 2048 (~10 us, the q=2 pipe floor). Cross-wave combine in
//   LDS keys; cross-quarter via atomicMin(slot) with packed (mono(d)<<32|m)
//   == lexicographic (d,m) == jnp.argmin first-min. 4th-arriving quarter
//   (group ticket) does the point-major coalesced cosine for its 128 points.
// blocks 512..519: stage-1 fused scan + cosine (verified R8/R12 body).
// Global 520-ticket on acc[2] finalizes out.
__global__ __launch_bounds__(256) void nn_cos_all(
        const float4* __restrict__ ps0, const float4* __restrict__ pt0,
        const float* __restrict__ sd0T, const float* __restrict__ td0T,
        const float4* __restrict__ ps1, const float4* __restrict__ pt1,
        const float* __restrict__ sd1T, const float* __restrict__ td1T,
        u64* slot, unsigned* tick, float* acc, float* __restrict__ out) {
    __shared__ __align__(16) float4 sm[1024];      // 16 KB target tile
    __shared__ u64 keys[512];                      // 4 KB combine keys
    __shared__ int last_flag;
    const int tid = threadIdx.x;
    const int bx  = blockIdx.x;
    const int w = tid >> 6, lane = tid & 63;

    if (bx < 512) {
        int b = bx >> 7, g = (bx >> 2) & 31, tq = bx & 3;
        const float4* tp = pt0 + b * N0 + tq * 1024;
        for (int i = tid; i < 1024; i += 256) {    // stage quarter, pre-scaled
            float4 q = tp[i];
            sm[i] = make_float4(-2.f * q.x, -2.f * q.y, -2.f * q.z, q.w);
        }
        __syncthreads();
        float4 P1 = ps0[b * N0 + g * 128 + lane];
        float4 P2 = ps0[b * N0 + g * 128 + 64 + lane];
        float b1 = FLT_MAX, b2 = FLT_MAX; int i1 = 0, i2 = 0;
        const int m0 = w * 256;                    // this wave's window
#pragma unroll 16
        for (int k = 0; k < 256; ++k) {
            float4 Q = sm[m0 + k];                 // broadcast, conflict-free
            float d1 = fmaf(P1.x, Q.x, fmaf(P1.y, Q.y, fmaf(P1.z, Q.z, Q.w)));
            float d2 = fmaf(P2.x, Q.x, fmaf(P2.y, Q.y, fmaf(P2.z, Q.z, Q.w)));
            if (d1 < b1) { b1 = d1; i1 = k; }      // ascending k: first-min
            if (d2 < b2) { b2 = d2; i2 = k; }
        }
        unsigned mbase = (unsigned)(tq * 1024 + m0);
        keys[w * 64 + lane]       = ((u64)fbits_mono(b1) << 32) | (mbase + i1);
        keys[256 + w * 64 + lane] = ((u64)fbits_mono(b2) << 32) | (mbase + i2);
        __syncthreads();
        if (tid < 128) {                           // one lane per point: 4-window combine
            int which = tid >> 6, l = tid & 63;
            const u64* kp = keys + which * 256 + l;
            u64 k0 = kp[0], k1 = kp[64], k2 = kp[128], k3 = kp[192];
            u64 ka = k0 < k1 ? k0 : k1;
            u64 kb = k2 < k3 ? k2 : k3;
            atomicMin(&slot[b * N0 + g * 128 + tid], ka < kb ? ka : kb);
        }
        __syncthreads();
        if (tid == 0) {                            // group ticket: 4th quarter does cos
            __threadfence();
            last_flag = (atomicAdd(&tick[b * 32 + g], 1u) == 3u);
        }
        __syncthreads();
        if (last_flag && tid < 128) {
            int n2 = g * 128 + tid;
            u64 kk = atomicAdd(&slot[b * N0 + n2], 0ull);   // coherent read
            int nearest = (int)(unsigned)(kk & 0xFFFFFFFFull);
            float cosv = cos_pm(sd0T, td0T, (size_t)b * N0 + n2,
                                (size_t)b * N0 + nearest);
            wave_reduce_atomic(cosv, acc + 0);     // waves 0,1 fully active
        }
    } else {
        int bb = bx - 512;
        int b = bb >> 1;
        const float4* tp = pt1 + b * N1;
        for (int i = tid; i < N1; i += 256) {
            float4 qq = tp[i];
            sm[i] = make_float4(-2.f * qq.x, -2.f * qq.y, -2.f * qq.z, qq.w);
        }
        __syncthreads();
        int n = (bb & 1) * 256 + tid;
        float4 P = ps1[b * N1 + n];
        float best = FLT_MAX; int bi = 0;
#pragma unroll 16
        for (int m = 0; m < N1; ++m) {
            float4 Q = sm[m];
            float d = fmaf(P.x, Q.x, fmaf(P.y, Q.y, fmaf(P.z, Q.z, Q.w)));
            if (d < best) { best = d; bi = m; }    // ascending m: first-min
        }
        float cosv = cos_pm(sd1T, td1T, (size_t)b * N1 + n, (size_t)b * N1 + bi);
        wave_reduce_atomic(cosv, acc + 1);
    }

    __syncthreads();                               // block's atomics all issued
    if (tid == 0) {
        __threadfence();
        unsigned old = atomicAdd((unsigned*)(acc + 2), 1u);
        if (old == 519u) {                         // last of 520 blocks
            float a0 = atomicAdd(acc + 0, 0.f);
            float a1 = atomicAdd(acc + 1, 0.f);
            out[0] = 1.f - 0.5f * (a0 * (1.f / 16384.f) + a1 * (1.f / 2048.f));
        }
    }
}

extern "C" void kernel_launch(void* const* d_in, const int* in_sizes, int n_in,
                              void* d_out, int out_size, void* d_ws, size_t ws_size,
                              hipStream_t stream) {
    const float* c_src = (const float*)d_in[0];   // [4,3,64,64,64]
    const float* c_tgt = (const float*)d_in[1];
    const float* sd0   = (const float*)d_in[2];   // [4,32,16,16,16]
    const float* td0   = (const float*)d_in[3];
    const float* sd1   = (const float*)d_in[4];   // [4,32,8,8,8]
    const float* td1   = (const float*)d_in[5];
    float* out = (float*)d_out;

    char* ws = (char*)d_ws;
    float*    acc  = (float*)ws;                   // [0]=sum0 [1]=sum1 [2]=global ticket
    unsigned* tick = (unsigned*)(ws + 256);        // 128 group tickets
    u64*      slot = (u64*)(ws + 2048);            // 16384 u64 (128 KB)
    float* t16a = (float*)(ws + 2048 + 131072);    // 786432 floats each
    float* t16b = t16a + 786432;
    float* t8a  = t16b + 786432;                   // 393216 floats each
    float* t8b  = t8a + 393216;
    float4* ps0 = (float4*)(t8b + 393216);         // 16384 float4
    float4* pt0 = ps0 + 16384;
    float4* ps1 = pt0 + 16384;                     // 2048 float4
    float4* pt1 = ps1 + 2048;
    float* sd0T = (float*)(pt1 + 2048);            // 524288 floats each
    float* td0T = sd0T + 524288;
    float* sd1T = td0T + 524288;                   // 65536 floats each
    float* td1T = sd1T + 65536;

    pass1_fused<<<dim3(1056, 2), 256, 0, stream>>>(c_src, c_tgt, sd0, td0, sd1, td1,
                                                   t16a, t16b, t8a, t8b,
                                                   sd0T, td0T, sd1T, td1T,
                                                   acc, tick, slot);
    pass2_both<<<1152, 256, 0, stream>>>(t16a, t16b, t8a, t8b, ps0, pt0, ps1, pt1);
    nn_cos_all<<<520, 256, 0, stream>>>(ps0, pt0, sd0T, td0T, ps1, pt1,
                                        sd1T, td1T, slot, tick, acc, out);
}

// Round 16
// 130.246 us; speedup vs baseline: 1.0171x; 1.0171x over previous
//
#include <hip/hip_runtime.h>
#include <cfloat>

typedef unsigned long long u64;

#define CDESC 32
#define N0 4096
#define N1 512

// sign-transformed float bits: monotone u32 over the float total order
__device__ __forceinline__ unsigned fbits_mono(float d) {
    unsigned b = __float_as_uint(d);
    return (d >= 0.f) ? (b | 0x80000000u) : ~b;
}

__device__ __forceinline__ void wave_reduce_atomic(float v, float* acc) {
#pragma unroll
    for (int off = 32; off > 0; off >>= 1) v += __shfl_down(v, off, 64);
    if ((threadIdx.x & 63) == 0) atomicAdd(acc, v);
}

// fp32 -> bf16 (round-half-up), returned in low 16 bits
__device__ __forceinline__ unsigned bf16_rhu(float f) {
    return (__float_as_uint(f) + 0x8000u) >> 16;
}
__device__ __forceinline__ float bf16_lo(unsigned p) {   // low half -> fp32
    return __uint_as_float(p << 16);
}
__device__ __forceinline__ float bf16_hi(unsigned p) {   // high half -> fp32
    return __uint_as_float(p & 0xFFFF0000u);
}

// ======================= K1: fused x-filter (both stages) + transpose =======================
// blocks 0..767 (x2 sides): one (channel, z) input plane staged to LDS once;
// compute BOTH S=16 (R=4) and S=8 (R=8) x-filter outputs (input read once).
// blocks 768..1055: descriptor transpose [b][32][N] -> [b][N][32]. Inits acc.
__global__ __launch_bounds__(256) void pass1_fused(
        const float* __restrict__ csrc, const float* __restrict__ ctgt,
        const float* __restrict__ sd0, const float* __restrict__ td0,
        const float* __restrict__ sd1, const float* __restrict__ td1,
        float* __restrict__ t16a, float* __restrict__ t16b,
        float* __restrict__ t8a,  float* __restrict__ t8b,
        float* __restrict__ sd0T, float* __restrict__ td0T,
        float* __restrict__ sd1T, float* __restrict__ td1T,
        float* __restrict__ acc) {
    __shared__ __align__(16) float sRow[4096];     // one 64x64 plane (16 KB)
    const int tid = threadIdx.x;
    const int bx  = blockIdx.x, by = blockIdx.y;
    if (by == 0 && bx == 0 && tid < 4) acc[tid] = 0.f;

    if (bx < 768) {
        int bc = bx >> 6, z = bx & 63;             // channel-plane, z-slice
        const float* in = by ? ctgt : csrc;
        float* o16 = by ? t16b : t16a;
        float* o8  = by ? t8b  : t8a;
        const float4* src = (const float4*)(in + (size_t)(bc * 64 + z) * 4096);
        float4* dst = (float4*)sRow;
#pragma unroll
        for (int k = 0; k < 4; ++k)                // coalesced 16 KB stage
            dst[tid + k * 256] = src[tid + k * 256];
        __syncthreads();
#pragma unroll
        for (int k = 0; k < 6; ++k) {              // 1536 outputs, 6/thread
            int o = tid + k * 256;
            if (o < 1024) {                        // S=16, R=4 (k=0..3: no divergence)
                int y = o >> 4, xo = o & 15;
                int j0 = 4 * xo - 2;
                float sum = 0.f, wsum = 0.f;
#pragma unroll
                for (int t = 0; t < 8; ++t) {
                    int j = j0 + t;
                    float w = 1.f - fabsf((float)t - 3.5f) / 4.f;
                    if (j >= 0 && j < 64) { sum = fmaf(w, sRow[y * 64 + j], sum); wsum += w; }
                }
                o16[bc * 65536 + z * 1024 + y * 16 + xo] = sum / wsum;
            } else {                               // S=8, R=8 (k=4,5)
                int o2 = o - 1024;
                int y = o2 >> 3, xo = o2 & 7;
                int j0 = 8 * xo - 4;
                float sum = 0.f, wsum = 0.f;
#pragma unroll
                for (int t = 0; t < 16; ++t) {
                    int j = j0 + t;
                    float w = 1.f - fabsf((float)t - 7.5f) / 8.f;
                    if (j >= 0 && j < 64) { sum = fmaf(w, sRow[y * 64 + j], sum); wsum += w; }
                }
                o8[bc * 32768 + z * 512 + y * 8 + xo] = sum / wsum;
            }
        }
    } else {
        // ---- transpose [b][32][N] -> [b][N][32], 64-point tiles (verified R7) ----
        __shared__ float tile[64 * 33];
        int tl = bx - 768;                         // 0..287
        const float* din; float* dout; int N, b, n0;
        if (tl < 256) { din = by ? td0 : sd0; dout = by ? td0T : sd0T;
                        N = N0; b = tl >> 6; n0 = (tl & 63) * 64; }
        else { tl -= 256; din = by ? td1 : sd1; dout = by ? td1T : sd1T;
               N = N1; b = tl >> 3; n0 = (tl & 7) * 64; }
#pragma unroll
        for (int i = 0; i < 8; ++i) {              // load: coalesced 64-float rows
            int idx = tid + i * 256;
            int c = idx >> 6, j = idx & 63;
            tile[j * 33 + c] = din[((size_t)b * CDESC + c) * N + n0 + j];
        }
        __syncthreads();
#pragma unroll
        for (int i = 0; i < 8; ++i) {              // store: contiguous 32-float points
            int idx = tid + i * 256;
            int p = idx >> 5, c = idx & 31;
            dout[((size_t)b * N + n0 + p) * CDESC + c] = tile[p * 33 + c];
        }
    }
}

// K2: both stages' y/z-filter, 8 sub-threads per point (verified R6/R7).
__global__ __launch_bounds__(256) void pass2_both(
        const float* __restrict__ t16a, const float* __restrict__ t16b,
        const float* __restrict__ t8a,  const float* __restrict__ t8b,
        float4* __restrict__ ps0, float4* __restrict__ pt0,
        float4* __restrict__ ps1, float4* __restrict__ pt1) {
    int gid = blockIdx.x * 256 + threadIdx.x;
    if (blockIdx.x < 1024) {
        int sub = gid & 7, p = gid >> 3;
        int side = p >> 14, r = p & 16383;
        int b = r >> 12, n = r & 4095;
        int x = n & 15, y = (n >> 4) & 15, z = n >> 8;
        const float* t = side ? t16b : t16a;
        float wy[8]; int jy[8];
        float wys = 0.f, wzs = 0.f;
#pragma unroll
        for (int tt = 0; tt < 8; ++tt) {
            float w = 1.f - fabsf((float)tt - 3.5f) * 0.25f;
            int j = 4 * y - 2 + tt;
            bool v = (unsigned)j < 64u;
            wy[tt] = v ? w : 0.f; jy[tt] = v ? j : 0; wys += wy[tt];
            int jz = 4 * z - 2 + tt;
            if ((unsigned)jz < 64u) wzs += w;
        }
        float a0 = 0.f, a1 = 0.f, a2 = 0.f;
        {
            float wz = 1.f - fabsf((float)sub - 3.5f) * 0.25f;
            int jz = 4 * z - 2 + sub;
            if ((unsigned)jz < 64u) {
                const float* bz = t + (size_t)b * 196608 + jz * 1024 + x;
#pragma unroll
                for (int ty = 0; ty < 8; ++ty) {
                    float w = wz * wy[ty];
                    const float* pr = bz + jy[ty] * 16;
                    a0 = fmaf(w, pr[0],      a0);
                    a1 = fmaf(w, pr[65536],  a1);
                    a2 = fmaf(w, pr[131072], a2);
                }
            }
        }
#pragma unroll
        for (int m = 1; m < 8; m <<= 1) {
            a0 += __shfl_xor(a0, m, 64);
            a1 += __shfl_xor(a1, m, 64);
            a2 += __shfl_xor(a2, m, 64);
        }
        if (sub == 0) {
            float inv = 1.f / (wys * wzs);
            a0 *= inv; a1 *= inv; a2 *= inv;
            float4* pts = side ? pt0 : ps0;
            pts[b * N0 + n] = make_float4(a0, a1, a2, a0 * a0 + a1 * a1 + a2 * a2);
        }
    } else {
        int g = gid - 262144;
        int sub = g & 7, p = g >> 3;
        int side = p >> 11, r = p & 2047;
        int b = r >> 9, n = r & 511;
        int x = n & 7, y = (n >> 3) & 7, z = n >> 6;
        const float* t = side ? t8b : t8a;
        constexpr int CS = 64 * 64 * 8;
        float wy[16]; int jy[16];
        float wys = 0.f, wzs = 0.f;
#pragma unroll
        for (int tt = 0; tt < 16; ++tt) {
            float w = 1.f - fabsf((float)tt - 7.5f) * 0.125f;
            int j = 8 * y - 4 + tt;
            bool v = (unsigned)j < 64u;
            wy[tt] = v ? w : 0.f; jy[tt] = v ? j : 0; wys += wy[tt];
            int jz = 8 * z - 4 + tt;
            if ((unsigned)jz < 64u) wzs += w;
        }
        float a0 = 0.f, a1 = 0.f, a2 = 0.f;
#pragma unroll
        for (int k = 0; k < 2; ++k) {
            int tt = 2 * sub + k;
            float wz = 1.f - fabsf((float)tt - 7.5f) * 0.125f;
            int jz = 8 * z - 4 + tt;
            if ((unsigned)jz < 64u) {
                const float* bz = t + b * 3 * CS + jz * (64 * 8) + x;
#pragma unroll 1
                for (int ty = 0; ty < 16; ++ty) {
                    float w = wz * wy[ty];
                    const float* pr = bz + jy[ty] * 8;
                    a0 = fmaf(w, pr[0],      a0);
                    a1 = fmaf(w, pr[CS],     a1);
                    a2 = fmaf(w, pr[2 * CS], a2);
                }
            }
        }
#pragma unroll
        for (int m = 1; m < 8; m <<= 1) {
            a0 += __shfl_xor(a0, m, 64);
            a1 += __shfl_xor(a1, m, 64);
            a2 += __shfl_xor(a2, m, 64);
        }
        if (sub == 0) {
            float inv = 1.f / (wys * wzs);
            a0 *= inv; a1 *= inv; a2 *= inv;
            float4* pts = side ? pt1 : ps1;
            pts[b * N1 + n] = make_float4(a0, a1, a2, a0 * a0 + a1 * a1 + a2 * a2);
        }
    }
}

// cosine of two point-major 32-float descriptors (coalesced float4 reads)
__device__ __forceinline__ float cos_pm(const float* __restrict__ sT,
                                        const float* __restrict__ tT,
                                        size_t si, size_t ti) {
    const float4* s = (const float4*)(sT + si * CDESC);
    const float4* t = (const float4*)(tT + ti * CDESC);
    float num = 0.f, s2 = 0.f, t2 = 0.f;
#pragma unroll
    for (int c = 0; c < 8; ++c) {
        float4 a = s[c], g = t[c];
        num = fmaf(a.x, g.x, fmaf(a.y, g.y, fmaf(a.z, g.z, fmaf(a.w, g.w, num))));
        s2  = fmaf(a.x, a.x, fmaf(a.y, a.y, fmaf(a.z, a.z, fmaf(a.w, a.w, s2))));
        t2  = fmaf(g.x, g.x, fmaf(g.y, g.y, fmaf(g.z, g.z, fmaf(g.w, g.w, t2))));
    }
    return num / (fmaxf(sqrtf(s2), 1e-8f) * fmaxf(sqrtf(t2), 1e-8f));
}

// ======================= K3: argmin + cosine, bf16-packed LDS targets =======================
// blocks 0..255: stage-0, block = (b, 64-point tile), R12's block-local shape
//   (measured best) with targets packed 4xbf16 (8 B): each ds_read_b128 now
//   serves TWO targets -> LDS reads/CU halve to 2048 (~10 us vs R12's 20.5).
//   Targets pre-scaled by -2 and rounded half-up to bf16 during staging; all
//   blocks see identical values, so argmin is consistent; lexicographic
//   (d,m)-key combine = exact first-min over the bf16-perturbed distances.
//   (Deliberate non-bit-exactness: |dloss| ~ 1e-3 << 0.0199 threshold.)
// blocks 256..263: stage-1 fp32 scan + cosine (bit-exact, verified body).
// Global 264-ticket on acc[2] finalizes out.
__global__ __launch_bounds__(256) void nn_cos_all(
        const float4* __restrict__ ps0, const float4* __restrict__ pt0,
        const float* __restrict__ sd0T, const float* __restrict__ td0T,
        const float4* __restrict__ ps1, const float4* __restrict__ pt1,
        const float* __restrict__ sd1T, const float* __restrict__ td1T,
        float* acc, float* __restrict__ out) {
    __shared__ __align__(16) uint2 sm[4096];       // 32 KB packed targets
    __shared__ u64 keys[256];
    const int tid = threadIdx.x;
    const int bx  = blockIdx.x;
    const int w = tid >> 6, lane = tid & 63;

    if (bx < 256) {
        int b = bx >> 6, ptile = bx & 63;
        const float4* tp = pt0 + b * N0;
        for (int i = tid; i < N0; i += 256) {      // stage + pack (16/thread)
            float4 q = tp[i];
            unsigned px = bf16_rhu(-2.f * q.x), py = bf16_rhu(-2.f * q.y);
            unsigned pz = bf16_rhu(-2.f * q.z), pw = bf16_rhu(q.w);
            sm[i] = make_uint2(px | (py << 16), pz | (pw << 16));
        }
        __syncthreads();
        int n = ptile * 64 + lane;
        float4 P = ps0[b * N0 + n];
        const uint4* smv = (const uint4*)sm;       // 1 read = 2 targets
        const int k0 = w * 512;                    // window base (uint4 units)
        float bA = FLT_MAX, bB = FLT_MAX; int iA = 0, iB = 0;
#pragma unroll 8
        for (int k = 0; k < 512; ++k) {
            uint4 Q = smv[k0 + k];                 // broadcast, conflict-free
            float dA = fmaf(P.x, bf16_lo(Q.x), fmaf(P.y, bf16_hi(Q.x),
                       fmaf(P.z, bf16_lo(Q.y), bf16_hi(Q.y))));
            float dB = fmaf(P.x, bf16_lo(Q.z), fmaf(P.y, bf16_hi(Q.z),
                       fmaf(P.z, bf16_lo(Q.w), bf16_hi(Q.w))));
            if (dA < bA) { bA = dA; iA = k; }      // ascending k: first-min per chain
            if (dB < bB) { bB = dB; iB = k; }
        }
        unsigned mA = (unsigned)(w * 1024 + 2 * iA);
        unsigned mB = (unsigned)(w * 1024 + 2 * iB + 1);
        u64 kA = ((u64)fbits_mono(bA) << 32) | mA;
        u64 kB = ((u64)fbits_mono(bB) << 32) | mB;
        keys[w * 64 + lane] = kA < kB ? kA : kB;   // lexicographic (d,m)
        __syncthreads();
        if (tid < 64) {                            // wave 0: one lane per point
            u64 q0 = keys[tid],       q1 = keys[tid + 64];
            u64 q2 = keys[tid + 128], q3 = keys[tid + 192];
            u64 qa = q0 < q1 ? q0 : q1;
            u64 qb = q2 < q3 ? q2 : q3;
            u64 kk = qa < qb ? qa : qb;
            int nearest = (int)(unsigned)(kk & 0xFFFFFFFFull);
            int n2 = ptile * 64 + tid;
            float cosv = cos_pm(sd0T, td0T, (size_t)b * N0 + n2,
                                (size_t)b * N0 + nearest);
            wave_reduce_atomic(cosv, acc + 0);
        }
    } else {
        int bb = bx - 256;
        int b = bb >> 1;
        float4* sm1 = (float4*)sm;                 // alias: fp32 targets (8 KB)
        const float4* tp = pt1 + b * N1;
        for (int i = tid; i < N1; i += 256) {
            float4 qq = tp[i];
            sm1[i] = make_float4(-2.f * qq.x, -2.f * qq.y, -2.f * qq.z, qq.w);
        }
        __syncthreads();
        int n = (bb & 1) * 256 + tid;
        float4 P = ps1[b * N1 + n];
        float best = FLT_MAX; int bi = 0;
#pragma unroll 16
        for (int m = 0; m < N1; ++m) {
            float4 Q = sm1[m];
            float d = fmaf(P.x, Q.x, fmaf(P.y, Q.y, fmaf(P.z, Q.z, Q.w)));
            if (d < best) { best = d; bi = m; }    // ascending m: first-min
        }
        float cosv = cos_pm(sd1T, td1T, (size_t)b * N1 + n, (size_t)b * N1 + bi);
        wave_reduce_atomic(cosv, acc + 1);
    }

    __syncthreads();                               // block's atomics all issued
    if (tid == 0) {
        __threadfence();
        unsigned old = atomicAdd((unsigned*)(acc + 2), 1u);
        if (old == 263u) {                         // last of 264 blocks
            float a0 = atomicAdd(acc + 0, 0.f);
            float a1 = atomicAdd(acc + 1, 0.f);
            out[0] = 1.f - 0.5f * (a0 * (1.f / 16384.f) + a1 * (1.f / 2048.f));
        }
    }
}

extern "C" void kernel_launch(void* const* d_in, const int* in_sizes, int n_in,
                              void* d_out, int out_size, void* d_ws, size_t ws_size,
                              hipStream_t stream) {
    const float* c_src = (const float*)d_in[0];   // [4,3,64,64,64]
    const float* c_tgt = (const float*)d_in[1];
    const float* sd0   = (const float*)d_in[2];   // [4,32,16,16,16]
    const float* td0   = (const float*)d_in[3];
    const float* sd1   = (const float*)d_in[4];   // [4,32,8,8,8]
    const float* td1   = (const float*)d_in[5];
    float* out = (float*)d_out;

    char* ws = (char*)d_ws;
    float* acc  = (float*)ws;                      // [0]=sum0 [1]=sum1 [2]=ticket
    float* t16a = (float*)(ws + 256);              // 786432 floats each
    float* t16b = t16a + 786432;
    float* t8a  = t16b + 786432;                   // 393216 floats each
    float* t8b  = t8a + 393216;
    float4* ps0 = (float4*)(t8b + 393216);         // 16384 float4
    float4* pt0 = ps0 + 16384;
    float4* ps1 = pt0 + 16384;                     // 2048 float4
    float4* pt1 = ps1 + 2048;
    float* sd0T = (float*)(pt1 + 2048);            // 524288 floats each
    float* td0T = sd0T + 524288;
    float* sd1T = td0T + 524288;                   // 65536 floats each
    float* td1T = sd1T + 65536;

    pass1_fused<<<dim3(1056, 2), 256, 0, stream>>>(c_src, c_tgt, sd0, td0, sd1, td1,
                                                   t16a, t16b, t8a, t8b,
                                                   sd0T, td0T, sd1T, td1T, acc);
    pass2_both<<<1152, 256, 0, stream>>>(t16a, t16b, t8a, t8b, ps0, pt0, ps1, pt1);
    nn_cos_all<<<264, 256, 0, stream>>>(ps0, pt0, sd0T, td0T, ps1, pt1,
                                        sd1T, td1T, acc, out);
}

// Round 17
// 129.990 us; speedup vs baseline: 1.0191x; 1.0020x over previous
//
#include <hip/hip_runtime.h>
#include <cfloat>

typedef unsigned long long u64;

#define CDESC 32
#define N0 4096
#define N1 512

// sign-transformed float bits: monotone u32 over the float total order
__device__ __forceinline__ unsigned fbits_mono(float d) {
    unsigned b = __float_as_uint(d);
    return (d >= 0.f) ? (b | 0x80000000u) : ~b;
}

__device__ __forceinline__ void wave_reduce_atomic(float v, float* acc) {
#pragma unroll
    for (int off = 32; off > 0; off >>= 1) v += __shfl_down(v, off, 64);
    if ((threadIdx.x & 63) == 0) atomicAdd(acc, v);
}

// ======================= K1: fused x-filter (both stages) + transpose =======================
// blocks 0..767 (x2 sides): one (channel, z) input plane staged to LDS once;
// compute BOTH S=16 (R=4) and S=8 (R=8) x-filter outputs (input read once).
// blocks 768..1055: descriptor transpose [b][32][N] -> [b][N][32]. Inits acc.
__global__ __launch_bounds__(256) void pass1_fused(
        const float* __restrict__ csrc, const float* __restrict__ ctgt,
        const float* __restrict__ sd0, const float* __restrict__ td0,
        const float* __restrict__ sd1, const float* __restrict__ td1,
        float* __restrict__ t16a, float* __restrict__ t16b,
        float* __restrict__ t8a,  float* __restrict__ t8b,
        float* __restrict__ sd0T, float* __restrict__ td0T,
        float* __restrict__ sd1T, float* __restrict__ td1T,
        float* __restrict__ acc) {
    __shared__ __align__(16) float sRow[4096];     // one 64x64 plane (16 KB)
    const int tid = threadIdx.x;
    const int bx  = blockIdx.x, by = blockIdx.y;
    if (by == 0 && bx == 0 && tid < 4) acc[tid] = 0.f;

    if (bx < 768) {
        int bc = bx >> 6, z = bx & 63;             // channel-plane, z-slice
        const float* in = by ? ctgt : csrc;
        float* o16 = by ? t16b : t16a;
        float* o8  = by ? t8b  : t8a;
        const float4* src = (const float4*)(in + (size_t)(bc * 64 + z) * 4096);
        float4* dst = (float4*)sRow;
#pragma unroll
        for (int k = 0; k < 4; ++k)                // coalesced 16 KB stage
            dst[tid + k * 256] = src[tid + k * 256];
        __syncthreads();
#pragma unroll
        for (int k = 0; k < 6; ++k) {              // 1536 outputs, 6/thread
            int o = tid + k * 256;
            if (o < 1024) {                        // S=16, R=4 (k=0..3: no divergence)
                int y = o >> 4, xo = o & 15;
                int j0 = 4 * xo - 2;
                float sum = 0.f, wsum = 0.f;
#pragma unroll
                for (int t = 0; t < 8; ++t) {
                    int j = j0 + t;
                    float w = 1.f - fabsf((float)t - 3.5f) / 4.f;
                    if (j >= 0 && j < 64) { sum = fmaf(w, sRow[y * 64 + j], sum); wsum += w; }
                }
                o16[bc * 65536 + z * 1024 + y * 16 + xo] = sum / wsum;
            } else {                               // S=8, R=8 (k=4,5)
                int o2 = o - 1024;
                int y = o2 >> 3, xo = o2 & 7;
                int j0 = 8 * xo - 4;
                float sum = 0.f, wsum = 0.f;
#pragma unroll
                for (int t = 0; t < 16; ++t) {
                    int j = j0 + t;
                    float w = 1.f - fabsf((float)t - 7.5f) / 8.f;
                    if (j >= 0 && j < 64) { sum = fmaf(w, sRow[y * 64 + j], sum); wsum += w; }
                }
                o8[bc * 32768 + z * 512 + y * 8 + xo] = sum / wsum;
            }
        }
    } else {
        // ---- transpose [b][32][N] -> [b][N][32], 64-point tiles (verified R7) ----
        __shared__ float tile[64 * 33];
        int tl = bx - 768;                         // 0..287
        const float* din; float* dout; int N, b, n0;
        if (tl < 256) { din = by ? td0 : sd0; dout = by ? td0T : sd0T;
                        N = N0; b = tl >> 6; n0 = (tl & 63) * 64; }
        else { tl -= 256; din = by ? td1 : sd1; dout = by ? td1T : sd1T;
               N = N1; b = tl >> 3; n0 = (tl & 7) * 64; }
#pragma unroll
        for (int i = 0; i < 8; ++i) {              // load: coalesced 64-float rows
            int idx = tid + i * 256;
            int c = idx >> 6, j = idx & 63;
            tile[j * 33 + c] = din[((size_t)b * CDESC + c) * N + n0 + j];
        }
        __syncthreads();
#pragma unroll
        for (int i = 0; i < 8; ++i) {              // store: contiguous 32-float points
            int idx = tid + i * 256;
            int p = idx >> 5, c = idx & 31;
            dout[((size_t)b * N + n0 + p) * CDESC + c] = tile[p * 33 + c];
        }
    }
}

// K2: both stages' y/z-filter, 8 sub-threads per point (verified R6/R7).
__global__ __launch_bounds__(256) void pass2_both(
        const float* __restrict__ t16a, const float* __restrict__ t16b,
        const float* __restrict__ t8a,  const float* __restrict__ t8b,
        float4* __restrict__ ps0, float4* __restrict__ pt0,
        float4* __restrict__ ps1, float4* __restrict__ pt1) {
    int gid = blockIdx.x * 256 + threadIdx.x;
    if (blockIdx.x < 1024) {
        int sub = gid & 7, p = gid >> 3;
        int side = p >> 14, r = p & 16383;
        int b = r >> 12, n = r & 4095;
        int x = n & 15, y = (n >> 4) & 15, z = n >> 8;
        const float* t = side ? t16b : t16a;
        float wy[8]; int jy[8];
        float wys = 0.f, wzs = 0.f;
#pragma unroll
        for (int tt = 0; tt < 8; ++tt) {
            float w = 1.f - fabsf((float)tt - 3.5f) * 0.25f;
            int j = 4 * y - 2 + tt;
            bool v = (unsigned)j < 64u;
            wy[tt] = v ? w : 0.f; jy[tt] = v ? j : 0; wys += wy[tt];
            int jz = 4 * z - 2 + tt;
            if ((unsigned)jz < 64u) wzs += w;
        }
        float a0 = 0.f, a1 = 0.f, a2 = 0.f;
        {
            float wz = 1.f - fabsf((float)sub - 3.5f) * 0.25f;
            int jz = 4 * z - 2 + sub;
            if ((unsigned)jz < 64u) {
                const float* bz = t + (size_t)b * 196608 + jz * 1024 + x;
#pragma unroll
                for (int ty = 0; ty < 8; ++ty) {
                    float w = wz * wy[ty];
                    const float* pr = bz + jy[ty] * 16;
                    a0 = fmaf(w, pr[0],      a0);
                    a1 = fmaf(w, pr[65536],  a1);
                    a2 = fmaf(w, pr[131072], a2);
                }
            }
        }
#pragma unroll
        for (int m = 1; m < 8; m <<= 1) {
            a0 += __shfl_xor(a0, m, 64);
            a1 += __shfl_xor(a1, m, 64);
            a2 += __shfl_xor(a2, m, 64);
        }
        if (sub == 0) {
            float inv = 1.f / (wys * wzs);
            a0 *= inv; a1 *= inv; a2 *= inv;
            float4* pts = side ? pt0 : ps0;
            pts[b * N0 + n] = make_float4(a0, a1, a2, a0 * a0 + a1 * a1 + a2 * a2);
        }
    } else {
        int g = gid - 262144;
        int sub = g & 7, p = g >> 3;
        int side = p >> 11, r = p & 2047;
        int b = r >> 9, n = r & 511;
        int x = n & 7, y = (n >> 3) & 7, z = n >> 6;
        const float* t = side ? t8b : t8a;
        constexpr int CS = 64 * 64 * 8;
        float wy[16]; int jy[16];
        float wys = 0.f, wzs = 0.f;
#pragma unroll
        for (int tt = 0; tt < 16; ++tt) {
            float w = 1.f - fabsf((float)tt - 7.5f) * 0.125f;
            int j = 8 * y - 4 + tt;
            bool v = (unsigned)j < 64u;
            wy[tt] = v ? w : 0.f; jy[tt] = v ? j : 0; wys += wy[tt];
            int jz = 8 * z - 4 + tt;
            if ((unsigned)jz < 64u) wzs += w;
        }
        float a0 = 0.f, a1 = 0.f, a2 = 0.f;
#pragma unroll
        for (int k = 0; k < 2; ++k) {
            int tt = 2 * sub + k;
            float wz = 1.f - fabsf((float)tt - 7.5f) * 0.125f;
            int jz = 8 * z - 4 + tt;
            if ((unsigned)jz < 64u) {
                const float* bz = t + b * 3 * CS + jz * (64 * 8) + x;
#pragma unroll 1
                for (int ty = 0; ty < 16; ++ty) {
                    float w = wz * wy[ty];
                    const float* pr = bz + jy[ty] * 8;
                    a0 = fmaf(w, pr[0],      a0);
                    a1 = fmaf(w, pr[CS],     a1);
                    a2 = fmaf(w, pr[2 * CS], a2);
                }
            }
        }
#pragma unroll
        for (int m = 1; m < 8; m <<= 1) {
            a0 += __shfl_xor(a0, m, 64);
            a1 += __shfl_xor(a1, m, 64);
            a2 += __shfl_xor(a2, m, 64);
        }
        if (sub == 0) {
            float inv = 1.f / (wys * wzs);
            a0 *= inv; a1 *= inv; a2 *= inv;
            float4* pts = side ? pt1 : ps1;
            pts[b * N1 + n] = make_float4(a0, a1, a2, a0 * a0 + a1 * a1 + a2 * a2);
        }
    }
}

// cosine of two point-major 32-float descriptors (coalesced float4 reads)
__device__ __forceinline__ float cos_pm(const float* __restrict__ sT,
                                        const float* __restrict__ tT,
                                        size_t si, size_t ti) {
    const float4* s = (const float4*)(sT + si * CDESC);
    const float4* t = (const float4*)(tT + ti * CDESC);
    float num = 0.f, s2 = 0.f, t2 = 0.f;
#pragma unroll
    for (int c = 0; c < 8; ++c) {
        float4 a = s[c], g = t[c];
        num = fmaf(a.x, g.x, fmaf(a.y, g.y, fmaf(a.z, g.z, fmaf(a.w, g.w, num))));
        s2  = fmaf(a.x, a.x, fmaf(a.y, a.y, fmaf(a.z, a.z, fmaf(a.w, a.w, s2))));
        t2  = fmaf(g.x, g.x, fmaf(g.y, g.y, fmaf(g.z, g.z, fmaf(g.w, g.w, t2))));
    }
    return num / (fmaxf(sqrtf(s2), 1e-8f) * fmaxf(sqrtf(t2), 1e-8f));
}

// ======================= K3: argmin + cosine (R12 measured-best body) =======================
// blocks 0..255: stage-0, block = (b, 64-point tile). ALL 4096 targets staged to
//   64 KB dynamic LDS once; 4 waves split m into 4x1024 windows; lane = point.
//   Broadcast ds_read_b128 (conflict-free). Cross-wave combine via packed
//   (mono(d)<<32 | m) keys in LDS (reused buffer) == lexicographic (d,m) min
//   == jnp.argmin first-min. Then point-major coalesced cosine.
// blocks 256..263: stage-1 fused scan + cosine.
// Global 264-ticket on acc[2] finalizes out.
__global__ __launch_bounds__(256) void nn_cos_all(
        const float4* __restrict__ ps0, const float4* __restrict__ pt0,
        const float* __restrict__ sd0T, const float* __restrict__ td0T,
        const float4* __restrict__ ps1, const float4* __restrict__ pt1,
        const float* __restrict__ sd1T, const float* __restrict__ td1T,
        float* acc, float* __restrict__ out) {
    extern __shared__ __align__(16) char smraw[];  // 64 KB dynamic
    float4* sm = (float4*)smraw;
    const int tid = threadIdx.x;
    const int bx  = blockIdx.x;

    if (bx < 256) {
        int b = bx >> 6, ptile = bx & 63;
        const float4* tp = pt0 + b * N0;
        for (int i = tid; i < N0; i += 256) {      // stage all 4096 targets (64 KB)
            float4 q = tp[i];
            sm[i] = make_float4(-2.f * q.x, -2.f * q.y, -2.f * q.z, q.w);
        }
        __syncthreads();
        int w = tid >> 6, lane = tid & 63;
        int n = ptile * 64 + lane;
        float4 P = ps0[b * N0 + n];
        float best = FLT_MAX; int bi = 0;
        const int m0 = w * 1024;                   // this wave's m-window
#pragma unroll 16
        for (int k = 0; k < 1024; ++k) {
            float4 Q = sm[m0 + k];                 // broadcast, conflict-free
            float d = fmaf(P.x, Q.x, fmaf(P.y, Q.y, fmaf(P.z, Q.z, Q.w)));
            if (d < best) { best = d; bi = k; }    // ascending m: first-min
        }
        u64 key = ((u64)fbits_mono(best) << 32) | (unsigned)(m0 + bi);
        __syncthreads();                           // everyone done reading sm
        u64* keys = (u64*)smraw;                   // reuse LDS for combine
        keys[w * 64 + lane] = key;
        __syncthreads();
        if (tid < 64) {
            u64 k0 = keys[tid],       k1 = keys[tid + 64];
            u64 k2 = keys[tid + 128], k3 = keys[tid + 192];
            u64 ka = k0 < k1 ? k0 : k1;
            u64 kb = k2 < k3 ? k2 : k3;
            u64 kk = ka < kb ? ka : kb;            // windows ascending + u64 min
            int nearest = (int)(unsigned)(kk & 0xFFFFFFFFull);
            int n2 = ptile * 64 + tid;
            float cosv = cos_pm(sd0T, td0T, (size_t)b * N0 + n2,
                                (size_t)b * N0 + nearest);
            wave_reduce_atomic(cosv, acc + 0);
        }
    } else {
        int bb = bx - 256;
        int b = bb >> 1;
        const float4* tp = pt1 + b * N1;
        for (int i = tid; i < N1; i += 256) {
            float4 qq = tp[i];
            sm[i] = make_float4(-2.f * qq.x, -2.f * qq.y, -2.f * qq.z, qq.w);
        }
        __syncthreads();
        int n = (bb & 1) * 256 + tid;
        float4 P = ps1[b * N1 + n];
        float best = FLT_MAX; int bi = 0;
#pragma unroll 16
        for (int m = 0; m < N1; ++m) {
            float4 Q = sm[m];
            float d = fmaf(P.x, Q.x, fmaf(P.y, Q.y, fmaf(P.z, Q.z, Q.w)));
            if (d < best) { best = d; bi = m; }    // ascending m: first-min
        }
        float cosv = cos_pm(sd1T, td1T, (size_t)b * N1 + n, (size_t)b * N1 + bi);
        wave_reduce_atomic(cosv, acc + 1);
    }

    __syncthreads();                               // block's atomics all issued
    if (tid == 0) {
        __threadfence();
        unsigned old = atomicAdd((unsigned*)(acc + 2), 1u);
        if (old == 263u) {                         // last of 264 blocks
            float a0 = atomicAdd(acc + 0, 0.f);
            float a1 = atomicAdd(acc + 1, 0.f);
            out[0] = 1.f - 0.5f * (a0 * (1.f / 16384.f) + a1 * (1.f / 2048.f));
        }
    }
}

extern "C" void kernel_launch(void* const* d_in, const int* in_sizes, int n_in,
                              void* d_out, int out_size, void* d_ws, size_t ws_size,
                              hipStream_t stream) {
    const float* c_src = (const float*)d_in[0];   // [4,3,64,64,64]
    const float* c_tgt = (const float*)d_in[1];
    const float* sd0   = (const float*)d_in[2];   // [4,32,16,16,16]
    const float* td0   = (const float*)d_in[3];
    const float* sd1   = (const float*)d_in[4];   // [4,32,8,8,8]
    const float* td1   = (const float*)d_in[5];
    float* out = (float*)d_out;

    char* ws = (char*)d_ws;
    float* acc  = (float*)ws;                      // [0]=sum0 [1]=sum1 [2]=ticket
    float* t16a = (float*)(ws + 256);              // 786432 floats each
    float* t16b = t16a + 786432;
    float* t8a  = t16b + 786432;                   // 393216 floats each
    float* t8b  = t8a + 393216;
    float4* ps0 = (float4*)(t8b + 393216);         // 16384 float4
    float4* pt0 = ps0 + 16384;
    float4* ps1 = pt0 + 16384;                     // 2048 float4
    float4* pt1 = ps1 + 2048;
    float* sd0T = (float*)(pt1 + 2048);            // 524288 floats each
    float* td0T = sd0T + 524288;
    float* sd1T = td0T + 524288;                   // 65536 floats each
    float* td1T = sd1T + 65536;

    pass1_fused<<<dim3(1056, 2), 256, 0, stream>>>(c_src, c_tgt, sd0, td0, sd1, td1,
                                                   t16a, t16b, t8a, t8b,
                                                   sd0T, td0T, sd1T, td1T, acc);
    pass2_both<<<1152, 256, 0, stream>>>(t16a, t16b, t8a, t8b, ps0, pt0, ps1, pt1);
    nn_cos_all<<<264, 256, 65536, stream>>>(ps0, pt0, sd0T, td0T, ps1, pt1,
                                            sd1T, td1T, acc, out);
}